// Round 10
// baseline (330.099 us; speedup 1.0000x reference)
//
#include <hip/hip_runtime.h>
#include <math.h>

// Problem constants
#define B_  8
#define N_  196
#define C_  12
#define D_  768
#define H_  12
#define R_  (B_*N_*C_)      // 18816 rows
#define KDIM 768
#define NQKV_PAD 768        // 720 real qkv cols padded to 768

typedef __attribute__((ext_vector_type(8))) short bf16x8;   // 8 bf16 = 4 VGPR
typedef __attribute__((ext_vector_type(4))) float f32x4;

__device__ inline unsigned short f2bf(float f) {
    union { float f; unsigned u; } v; v.f = f;
    unsigned r = v.u + 0x7fffu + ((v.u >> 16) & 1u);   // RNE
    return (unsigned short)(r >> 16);
}
__device__ inline float bf2f(unsigned short h) {
    union { unsigned u; float f; } v; v.u = ((unsigned)h) << 16; return v.f;
}

// ---------------------------------------------------------------------------
// fp32 -> (bf16 hi, bf16 lo) elementwise split. n must be a multiple of 4.
// ---------------------------------------------------------------------------
__global__ __launch_bounds__(256) void convert_split(
    const float* __restrict__ in, unsigned short* __restrict__ hi,
    unsigned short* __restrict__ lo, int n)
{
    int i = (blockIdx.x * 256 + threadIdx.x) * 4;
    if (i >= n) return;
    float4 v = *reinterpret_cast<const float4*>(in + i);
    ushort4 h, l;
    h.x = f2bf(v.x); l.x = f2bf(v.x - bf2f(h.x));
    h.y = f2bf(v.y); l.y = f2bf(v.y - bf2f(h.y));
    h.z = f2bf(v.z); l.z = f2bf(v.z - bf2f(h.z));
    h.w = f2bf(v.w); l.w = f2bf(v.w - bf2f(h.w));
    *reinterpret_cast<ushort4*>(hi + i) = h;
    *reinterpret_cast<ushort4*>(lo + i) = l;
}

// One launch for both weight conversions.
__global__ __launch_bounds__(256) void convert_weights(
    const float* __restrict__ wc, const float* __restrict__ ws,
    const float* __restrict__ wp,
    unsigned short* __restrict__ wqkv_hi, unsigned short* __restrict__ wqkv_lo,
    unsigned short* __restrict__ wp_hi,   unsigned short* __restrict__ wp_lo)
{
    int i = (blockIdx.x * 256 + threadIdx.x) * 4;
    unsigned short* dh; unsigned short* dl; float4 v; int off;
    if (i < 768 * 768) {
        const int r = i / 768, k = i % 768;
        v = make_float4(0.f, 0.f, 0.f, 0.f);
        if (r < 144)      v = *reinterpret_cast<const float4*>(wc + r * 768 + k);
        else if (r < 720) v = *reinterpret_cast<const float4*>(ws + (r - 144) * 768 + k);
        dh = wqkv_hi; dl = wqkv_lo; off = i;
    } else {
        off = i - 768 * 768;
        if (off >= 768 * 768) return;
        v = *reinterpret_cast<const float4*>(wp + off);
        dh = wp_hi; dl = wp_lo;
    }
    ushort4 h, l;
    h.x = f2bf(v.x); l.x = f2bf(v.x - bf2f(h.x));
    h.y = f2bf(v.y); l.y = f2bf(v.y - bf2f(h.y));
    h.z = f2bf(v.z); l.z = f2bf(v.z - bf2f(h.z));
    h.w = f2bf(v.w); l.w = f2bf(v.w - bf2f(h.w));
    *reinterpret_cast<ushort4*>(dh + off) = h;
    *reinterpret_cast<ushort4*>(dl + off) = l;
}

// ---------------------------------------------------------------------------
// bf16x3 split MFMA GEMM. THIS ROUND: B operand loaded DIRECTLY global->VGPR
// (weights are L2/L3-hot, shared by all M-blocks under nt-fast swizzle);
// only A is LDS-staged (dbuf 2x16KB = 32 KB). Halves LDS reads AND staging
// writes per K-step; ~3 blocks/CU. Sync invariant: issue [B(t) x8][A(t+1) x4],
// vmcnt(4) drains tile-t traffic, leaves next-tile A in flight; B-reg deps
// are compiler-tracked.
// ---------------------------------------------------------------------------
#define BM 128
#define BN 128
#define BK 32

__device__ inline void gload16(const unsigned short* src, void* ldsbase) {
    __builtin_amdgcn_global_load_lds(
        (const __attribute__((address_space(1))) unsigned int*)src,
        (__attribute__((address_space(3))) unsigned int*)ldsbase, 16, 0, 0);
}

__global__ __launch_bounds__(256) void gemm_bf16x3(
    const unsigned short* __restrict__ Ahi, const unsigned short* __restrict__ Alo,
    const unsigned short* __restrict__ Bhi, const unsigned short* __restrict__ Blo,
    const float* __restrict__ bias,
    float* __restrict__ outp, int M, int Nt, int K, int ntiles)
{
    __shared__ unsigned short sAhi[2][BM][BK], sAlo[2][BM][BK];

    const int nwg = gridDim.x;
    const int bid = blockIdx.x;
    const int xcd = bid & 7, slot = bid >> 3;
    const int q = nwg >> 3, r = nwg & 7;
    const int wg = (xcd < r ? xcd * (q + 1) : r * (q + 1) + (xcd - r) * q) + slot;
    const int mt = wg / ntiles, nt = wg - mt * ntiles;   // nt fast: A-panel reuse
    const int m0 = mt * BM, n0 = nt * BN;

    const int tid = threadIdx.x;
    const int w = tid >> 6, l = tid & 63;
    const int wr = (w >> 1) * 64, wc = (w & 1) * 64;

    f32x4 acc[4][4];
    #pragma unroll
    for (int i = 0; i < 4; ++i)
        #pragma unroll
        for (int j = 0; j < 4; ++j)
            acc[i][j] = (f32x4){0.f, 0.f, 0.f, 0.f};

    // A staging geometry: 8KB per array per buffer; wave w covers bytes
    // [w*1024,+1024) and [4096+w*1024,+1024); lane adds l*16.
    const int seg0 = w * 1024, seg1 = 4096 + w * 1024;
    const int o0 = seg0 + l * 16, o1 = seg1 + l * 16;
    const int r0 = o0 >> 6, c0 = (o0 & 63) >> 1;
    const int r1 = o1 >> 6, c1 = (o1 & 63) >> 1;

    const int lr = l & 15;
    const int kb = (l >> 4) * 8;

    // B fragment element-offsets (row-gather; lanes {l,l+16,l+32,l+48} cover
    // one row's 64 contiguous bytes -> L2-friendly 64B segments)
    size_t boff[4];
    #pragma unroll
    for (int fn = 0; fn < 4; ++fn)
        boff[fn] = (size_t)(n0 + wc + fn * 16 + lr) * K + kb;

#define STAGE_A(buf, kk)                                                                   \
    gload16(Ahi + (size_t)(m0 + r0) * K + (kk) + c0, (char*)sAhi + (buf) * 8192 + seg0);   \
    gload16(Ahi + (size_t)(m0 + r1) * K + (kk) + c1, (char*)sAhi + (buf) * 8192 + seg1);   \
    gload16(Alo + (size_t)(m0 + r0) * K + (kk) + c0, (char*)sAlo + (buf) * 8192 + seg0);   \
    gload16(Alo + (size_t)(m0 + r1) * K + (kk) + c1, (char*)sAlo + (buf) * 8192 + seg1);

    STAGE_A(0, 0);

    const int KT = K / BK;   // 24
    int cur = 0;
    for (int t = 0; t < KT; ++t) {
        // B fragments for tile t -> regs (compiler tracks deps + inserts waits)
        bf16x8 bh[4], bl[4];
        #pragma unroll
        for (int fn = 0; fn < 4; ++fn) {
            bh[fn] = *reinterpret_cast<const bf16x8*>(Bhi + boff[fn] + t * BK);
            bl[fn] = *reinterpret_cast<const bf16x8*>(Blo + boff[fn] + t * BK);
        }
        if (t + 1 < KT) {
            STAGE_A(cur ^ 1, (t + 1) * BK);                    // 4 loads in flight
            asm volatile("s_waitcnt vmcnt(4)" ::: "memory");   // drain tile t
        } else {
            asm volatile("s_waitcnt vmcnt(0)" ::: "memory");
        }
        asm volatile("s_barrier" ::: "memory");                // A(t) visible

        bf16x8 ah[4], al[4];
        #pragma unroll
        for (int fm = 0; fm < 4; ++fm) {
            ah[fm] = *reinterpret_cast<const bf16x8*>(&sAhi[cur][wr + fm * 16 + lr][kb]);
            al[fm] = *reinterpret_cast<const bf16x8*>(&sAlo[cur][wr + fm * 16 + lr][kb]);
        }
        #pragma unroll
        for (int fn = 0; fn < 4; ++fn) {
            #pragma unroll
            for (int fm = 0; fm < 4; ++fm) {
                acc[fm][fn] = __builtin_amdgcn_mfma_f32_16x16x32_bf16(ah[fm], bh[fn], acc[fm][fn], 0, 0, 0);
                acc[fm][fn] = __builtin_amdgcn_mfma_f32_16x16x32_bf16(ah[fm], bl[fn], acc[fm][fn], 0, 0, 0);
                acc[fm][fn] = __builtin_amdgcn_mfma_f32_16x16x32_bf16(al[fm], bh[fn], acc[fm][fn], 0, 0, 0);
            }
        }
        // all ds_reads of [cur] consumed before this barrier; next STAGE_A
        // (issued after it) may overwrite [cur].
        asm volatile("s_barrier" ::: "memory");
        cur ^= 1;
    }
#undef STAGE_A

    const int rg = (l >> 4) * 4;
    #pragma unroll
    for (int fm = 0; fm < 4; ++fm) {
        #pragma unroll
        for (int fn = 0; fn < 4; ++fn) {
            const int row = m0 + wr + fm * 16 + rg;
            const int col = n0 + wc + fn * 16 + lr;
            const float bv = bias ? bias[col] : 0.f;
            #pragma unroll
            for (int rr = 0; rr < 4; ++rr)
                outp[(size_t)(row + rr) * Nt + col] = acc[fm][fn][rr] + bv;
        }
    }
}

// ---------------------------------------------------------------------------
// MFMA spatial attention (round-9 verified: simplified softmax). Unchanged.
// ---------------------------------------------------------------------------
__global__ __launch_bounds__(256) void spatial_attn_mfma(
    const float* __restrict__ qkv,
    float* __restrict__ xs_out)
{
    __shared__ unsigned short Kl[224][40];
    __shared__ unsigned short Ql[208][40];
    __shared__ unsigned short VtH[16][232];
    __shared__ unsigned short Pb[4][16][40];

    const int bid = blockIdx.x;                // 1152 = 8*12*12
    const int c = bid % 12;
    const int h = (bid / 12) % 12;
    const int b = bid / 144;
    const int tid = threadIdx.x;
    const int w = tid >> 6, l = tid & 63;
    const int fl = l & 15, g = l >> 4;

    for (int idx = tid; idx < N_ * 16; idx += 256) {
        const int n = idx >> 4, e = idx & 15;
        const float* base = qkv + (size_t)((b * N_ + n) * 12 + c) * NQKV_PAD + 144 + h * 16 + e;
        const float qv = base[0] * 0.25f;
        const float kv = base[192];
        const float vv = base[384];
        const unsigned short qh = f2bf(qv), kh = f2bf(kv);
        Ql[n][e]      = qh;  Ql[n][16 + e] = f2bf(qv - bf2f(qh));
        Kl[n][e]      = kh;  Kl[n][16 + e] = f2bf(kv - bf2f(kh));
        VtH[e][n]     = f2bf(vv);
    }
    for (int idx = tid; idx < 16 * 28; idx += 256) {
        const int d = idx / 28, n = 196 + idx % 28;
        VtH[d][n] = 0;
    }
    __syncthreads();

    f32x4 accO[4];
    float lsum[4];
    #pragma unroll
    for (int j = 0; j < 4; ++j) {
        accO[j] = (f32x4){0.f, 0.f, 0.f, 0.f};
        lsum[j] = 0.f;
    }
    const f32x4 zf = (f32x4){0.f, 0.f, 0.f, 0.f};
    const bf16x8 zb = (bf16x8){0, 0, 0, 0, 0, 0, 0, 0};

    for (int ch = 0; ch < 7; ++ch) {
        const int kb0 = ch * 32;
        const bf16x8 A1a = *reinterpret_cast<const bf16x8*>(&Kl[kb0 + fl][8 * g]);
        const bf16x8 A1b = *reinterpret_cast<const bf16x8*>(&Kl[kb0 + 16 + fl][8 * g]);
        const bf16x8 A2a = *reinterpret_cast<const bf16x8*>(&Kl[kb0 + fl][8 * (g & 1)]);
        const bf16x8 A2b = *reinterpret_cast<const bf16x8*>(&Kl[kb0 + 16 + fl][8 * (g & 1)]);
        const bf16x8 AvH = *reinterpret_cast<const bf16x8*>(&VtH[fl][kb0 + 8 * g]);

        #pragma unroll
        for (int j = 0; j < 4; ++j) {
            const int qt = w + 4 * j;
            if (qt > 12) continue;
            const int qrow = qt * 16 + fl;
            const bf16x8 Bq1 = *reinterpret_cast<const bf16x8*>(&Ql[qrow][8 * (g & 1)]);
            bf16x8 Bq2 = *reinterpret_cast<const bf16x8*>(&Ql[qrow][16 + 8 * (g & 1)]);
            if (g >= 2) Bq2 = zb;

            f32x4 T0 = zf, T1 = zf;
            T0 = __builtin_amdgcn_mfma_f32_16x16x32_bf16(A1a, Bq1, T0, 0, 0, 0);
            T0 = __builtin_amdgcn_mfma_f32_16x16x32_bf16(A2a, Bq2, T0, 0, 0, 0);
            T1 = __builtin_amdgcn_mfma_f32_16x16x32_bf16(A1b, Bq1, T1, 0, 0, 0);
            T1 = __builtin_amdgcn_mfma_f32_16x16x32_bf16(A2b, Bq2, T1, 0, 0, 0);

            float s0 = T0[0], s1 = T0[1], s2 = T0[2], s3 = T0[3];
            float s4 = T1[0], s5 = T1[1], s6 = T1[2], s7 = T1[3];
            if (ch == 6) {                      // mask pad k-rows (expf(-1e30)=0)
                const int kg = kb0 + 4 * g;
                if (kg + 0 >= 196) s0 = -1e30f;
                if (kg + 1 >= 196) s1 = -1e30f;
                if (kg + 2 >= 196) s2 = -1e30f;
                if (kg + 3 >= 196) s3 = -1e30f;
                s4 = -1e30f; s5 = -1e30f; s6 = -1e30f; s7 = -1e30f;
            }
            const float p0 = __expf(s0), p1 = __expf(s1);
            const float p2 = __expf(s2), p3 = __expf(s3);
            const float p4 = __expf(s4), p5 = __expf(s5);
            const float p6 = __expf(s6), p7 = __expf(s7);
            lsum[j] += ((p0 + p1) + (p2 + p3)) + ((p4 + p5) + (p6 + p7));

            uint2 whi0, whi1;
            whi0.x = (unsigned)f2bf(p0) | ((unsigned)f2bf(p1) << 16);
            whi0.y = (unsigned)f2bf(p2) | ((unsigned)f2bf(p3) << 16);
            whi1.x = (unsigned)f2bf(p4) | ((unsigned)f2bf(p5) << 16);
            whi1.y = (unsigned)f2bf(p6) | ((unsigned)f2bf(p7) << 16);
            *reinterpret_cast<uint2*>(&Pb[w][fl][4 * g])      = whi0;
            *reinterpret_cast<uint2*>(&Pb[w][fl][16 + 4 * g]) = whi1;

            const bf16x8 BpH = *reinterpret_cast<const bf16x8*>(&Pb[w][fl][8 * g]);
            accO[j] = __builtin_amdgcn_mfma_f32_16x16x32_bf16(AvH, BpH, accO[j], 0, 0, 0);
        }
    }

    #pragma unroll
    for (int j = 0; j < 4; ++j) {
        const int qt = w + 4 * j;
        if (qt > 12) continue;
        float ls = lsum[j];
        ls += __shfl_xor(ls, 16);
        ls += __shfl_xor(ls, 32);
        const int n = qt * 16 + fl;
        if (n < 196) {
            const float inv = 1.f / ls;
            float4 o;
            o.x = accO[j][0] * inv; o.y = accO[j][1] * inv;
            o.z = accO[j][2] * inv; o.w = accO[j][3] * inv;
            const size_t base = ((size_t)((b * 12 + h) * N_ + n) * 12 + c) * 16 + 4 * g;
            *reinterpret_cast<float4*>(&xs_out[base]) = o;
        }
    }
}

// ---------------------------------------------------------------------------
// Channel attention + outer-product combine, 4 rows per 256-thread block.
// ---------------------------------------------------------------------------
__global__ __launch_bounds__(256) void chan_attn_combine4(
    const float* __restrict__ qkv,
    const float* __restrict__ xs,
    unsigned short* __restrict__ yhi,
    unsigned short* __restrict__ ylo)
{
    const int sub = threadIdx.x >> 6;
    const int t = threadIdx.x & 63;
    const int flat = blockIdx.x * 4 + sub;     // (b*12+h)*196 + n
    const int n = flat % 196;
    const int h = (flat / 196) % 12;
    const int b = flat / 2352;

    __shared__ float sQ[4][12][4], sK[4][12][4], sV[4][12][4], sXc[4][12][4];
    __shared__ float sXs[4][12][16];

    for (int idx = t; idx < 144; idx += 64) {
        const int c = idx / 12, rem = idx % 12, s = rem >> 2, e = rem & 3;
        const float v = qkv[(size_t)((b * N_ + n) * 12 + c) * NQKV_PAD + s * 48 + h * 4 + e];
        if (s == 0) sQ[sub][c][e] = v;
        else if (s == 1) sK[sub][c][e] = v;
        else sV[sub][c][e] = v;
    }
    for (int idx = t; idx < 192; idx += 64) {
        const int c = idx >> 4, j = idx & 15;
        sXs[sub][c][j] = xs[((size_t)flat * 12 + c) * 16 + j];
    }
    __syncthreads();

    if (t < 12) {
        const int c = t;
        float s[12];
        float m = -INFINITY;
        #pragma unroll
        for (int c2 = 0; c2 < 12; ++c2) {
            float d = 0.f;
            #pragma unroll
            for (int e = 0; e < 4; ++e) d += sQ[sub][c][e] * sK[sub][c2][e];
            s[c2] = d * 0.5f;
            m = fmaxf(m, s[c2]);
        }
        float lsum = 0.f;
        #pragma unroll
        for (int c2 = 0; c2 < 12; ++c2) { s[c2] = __expf(s[c2] - m); lsum += s[c2]; }
        const float inv = 1.f / lsum;
        #pragma unroll
        for (int i = 0; i < 4; ++i) {
            float a = 0.f;
            #pragma unroll
            for (int c2 = 0; c2 < 12; ++c2) a += s[c2] * sV[sub][c2][i];
            sXc[sub][c][i] = a * inv;
        }
    }
    __syncthreads();

    const size_t yrow = ((size_t)(b * N_ + n) * 12 + h) * (size_t)D_;
    #pragma unroll
    for (int k = 0; k < 12; ++k) {
        const float v = sXc[sub][k][t >> 4] * sXs[sub][k][t & 15];
        const unsigned short hv = f2bf(v);
        yhi[yrow + k * 64 + t] = hv;
        ylo[yrow + k * 64 + t] = f2bf(v - bf2f(hv));
    }
}

// ---------------------------------------------------------------------------
extern "C" void kernel_launch(void* const* d_in, const int* in_sizes, int n_in,
                              void* d_out, int out_size, void* d_ws, size_t ws_size,
                              hipStream_t stream) {
    const float* x       = (const float*)d_in[0];
    const float* w_qkv_c = (const float*)d_in[1];
    const float* w_qkv_s = (const float*)d_in[2];
    const float* w_proj  = (const float*)d_in[3];
    const float* b_proj  = (const float*)d_in[4];
    float* out = (float*)d_out;

    unsigned short* xhi = (unsigned short*)d_ws;
    unsigned short* xlo = xhi + (size_t)R_ * KDIM;
    unsigned short* wqkv_hi = xlo + (size_t)R_ * KDIM;
    unsigned short* wqkv_lo = wqkv_hi + (size_t)768 * 768;
    unsigned short* wp_hi   = wqkv_lo + (size_t)768 * 768;
    unsigned short* wp_lo   = wp_hi + (size_t)768 * 768;
    float* qkv = (float*)(wp_lo + (size_t)768 * 768);
    float* xs  = qkv + (size_t)R_ * NQKV_PAD;
    unsigned short* yhi = xhi;   // alias: x splits dead after qkv GEMM
    unsigned short* ylo = xlo;

    convert_split<<<(R_ * KDIM) / 1024, 256, 0, stream>>>(x, xhi, xlo, R_ * KDIM);
    convert_weights<<<(2 * 768 * 768) / 1024, 256, 0, stream>>>(
        w_qkv_c, w_qkv_s, w_proj, wqkv_hi, wqkv_lo, wp_hi, wp_lo);

    {
        const int mtiles = R_ / BM, ntiles = NQKV_PAD / BN;
        gemm_bf16x3<<<mtiles * ntiles, 256, 0, stream>>>(
            xhi, xlo, wqkv_hi, wqkv_lo, nullptr, qkv, R_, NQKV_PAD, KDIM, ntiles);
    }
    spatial_attn_mfma<<<B_ * H_ * C_, 256, 0, stream>>>(qkv, xs);
    chan_attn_combine4<<<(B_ * H_ * N_) / 4, 256, 0, stream>>>(qkv, xs, yhi, ylo);
    {
        const int mtiles = R_ / BM, ntiles = D_ / BN;
        gemm_bf16x3<<<mtiles * ntiles, 256, 0, stream>>>(
            yhi, ylo, wp_hi, wp_lo, b_proj, out, R_, D_, KDIM, ntiles);
    }
}

// Round 13
// 214.551 us; speedup vs baseline: 1.5386x; 1.5386x over previous
//
#include <hip/hip_runtime.h>
#include <math.h>

// Problem constants
#define B_  8
#define N_  196
#define C_  12
#define D_  768
#define H_  12
#define R_  (B_*N_*C_)      // 18816 rows
#define KDIM 768
#define NQKV_PAD 768        // 720 real qkv cols padded to 768

typedef _Float16 f16x8 __attribute__((ext_vector_type(8)));   // 8 f16 = 4 VGPR
typedef __attribute__((ext_vector_type(4))) float f32x4;

__device__ inline unsigned short f2h(float f) {
    union { _Float16 h; unsigned short u; } v; v.h = (_Float16)f; return v.u;
}
__device__ inline float h2f(unsigned short u) {
    union { unsigned short u; _Float16 h; } v; v.u = u; return (float)v.h;
}

// ---------------------------------------------------------------------------
// fp32 -> (f16 hi, f16 lo) elementwise split. n must be a multiple of 4.
// ---------------------------------------------------------------------------
__global__ __launch_bounds__(256) void convert_split(
    const float* __restrict__ in, unsigned short* __restrict__ hi,
    unsigned short* __restrict__ lo, int n)
{
    int i = (blockIdx.x * 256 + threadIdx.x) * 4;
    if (i >= n) return;
    float4 v = *reinterpret_cast<const float4*>(in + i);
    ushort4 h, l;
    h.x = f2h(v.x); l.x = f2h(v.x - h2f(h.x));
    h.y = f2h(v.y); l.y = f2h(v.y - h2f(h.y));
    h.z = f2h(v.z); l.z = f2h(v.z - h2f(h.z));
    h.w = f2h(v.w); l.w = f2h(v.w - h2f(h.w));
    *reinterpret_cast<ushort4*>(hi + i) = h;
    *reinterpret_cast<ushort4*>(lo + i) = l;
}

// One launch: wqkv (packed 768x768, rows 720+ zero) and wp, SINGLE f16 each.
__global__ __launch_bounds__(256) void convert_weights(
    const float* __restrict__ wc, const float* __restrict__ ws,
    const float* __restrict__ wp,
    unsigned short* __restrict__ wqkv_h, unsigned short* __restrict__ wp_h)
{
    int i = (blockIdx.x * 256 + threadIdx.x) * 4;
    unsigned short* dh; float4 v; int off;
    if (i < 768 * 768) {
        const int r = i / 768, k = i % 768;
        v = make_float4(0.f, 0.f, 0.f, 0.f);
        if (r < 144)      v = *reinterpret_cast<const float4*>(wc + r * 768 + k);
        else if (r < 720) v = *reinterpret_cast<const float4*>(ws + (r - 144) * 768 + k);
        dh = wqkv_h; off = i;
    } else {
        off = i - 768 * 768;
        if (off >= 768 * 768) return;
        v = *reinterpret_cast<const float4*>(wp + off);
        dh = wp_h;
    }
    ushort4 h;
    h.x = f2h(v.x); h.y = f2h(v.y); h.z = f2h(v.z); h.w = f2h(v.w);
    *reinterpret_cast<ushort4*>(dh + off) = h;
}

// ---------------------------------------------------------------------------
// f16x2 split MFMA GEMM: out = (Ahi+Alo) @ Bh^T, 2 MFMA terms (A exact to
// 2^-22, B single f16). r9-verified structure: 2-phase dbuf, counted vmcnt,
// chunked XCD swizzle, nt-fast. LDS 48KB -> 3 blocks/CU.
// ---------------------------------------------------------------------------
#define BM 128
#define BN 128
#define BK 32

__device__ inline void gload16(const unsigned short* src, void* ldsbase) {
    __builtin_amdgcn_global_load_lds(
        (const __attribute__((address_space(1))) unsigned int*)src,
        (__attribute__((address_space(3))) unsigned int*)ldsbase, 16, 0, 0);
}

__global__ __launch_bounds__(256) void gemm_f16x2(
    const unsigned short* __restrict__ Ahi, const unsigned short* __restrict__ Alo,
    const unsigned short* __restrict__ Bh,
    const float* __restrict__ bias,
    float* __restrict__ outp, int M, int Nt, int K, int ntiles)
{
    __shared__ unsigned short sAhi[2][BM][BK], sAlo[2][BM][BK], sB[2][BN][BK];

    const int nwg = gridDim.x;
    const int bid = blockIdx.x;
    const int xcd = bid & 7, slot = bid >> 3;
    const int q = nwg >> 3, r = nwg & 7;
    const int wg = (xcd < r ? xcd * (q + 1) : r * (q + 1) + (xcd - r) * q) + slot;
    const int mt = wg / ntiles, nt = wg - mt * ntiles;   // nt fast: A-panel reuse
    const int m0 = mt * BM, n0 = nt * BN;

    const int tid = threadIdx.x;
    const int w = tid >> 6, l = tid & 63;
    const int wr = (w >> 1) * 64, wc = (w & 1) * 64;

    f32x4 acc[4][4];
    #pragma unroll
    for (int i = 0; i < 4; ++i)
        #pragma unroll
        for (int j = 0; j < 4; ++j)
            acc[i][j] = (f32x4){0.f, 0.f, 0.f, 0.f};

    const int seg0 = w * 1024, seg1 = 4096 + w * 1024;
    const int o0 = seg0 + l * 16, o1 = seg1 + l * 16;
    const int r0 = o0 >> 6, c0 = (o0 & 63) >> 1;
    const int r1 = o1 >> 6, c1 = (o1 & 63) >> 1;

    const int lr = l & 15;
    const int kb = (l >> 4) * 8;

#define STAGE(buf, kk)                                                                     \
    gload16(Ahi + (size_t)(m0 + r0) * K + (kk) + c0, (char*)sAhi + (buf) * 8192 + seg0);   \
    gload16(Ahi + (size_t)(m0 + r1) * K + (kk) + c1, (char*)sAhi + (buf) * 8192 + seg1);   \
    gload16(Alo + (size_t)(m0 + r0) * K + (kk) + c0, (char*)sAlo + (buf) * 8192 + seg0);   \
    gload16(Alo + (size_t)(m0 + r1) * K + (kk) + c1, (char*)sAlo + (buf) * 8192 + seg1);   \
    gload16(Bh  + (size_t)(n0 + r0) * K + (kk) + c0, (char*)sB   + (buf) * 8192 + seg0);   \
    gload16(Bh  + (size_t)(n0 + r1) * K + (kk) + c1, (char*)sB   + (buf) * 8192 + seg1);

    STAGE(0, 0);                       // 6 loads in flight

    const int KT = K / BK;             // 24
    int cur = 0;
    for (int t = 0; t < KT; ++t) {
        if (t + 1 < KT) {
            STAGE(cur ^ 1, (t + 1) * BK);                      // +6 -> 12 in flight
            asm volatile("s_waitcnt vmcnt(6)" ::: "memory");   // drain tile t only
        } else {
            asm volatile("s_waitcnt vmcnt(0)" ::: "memory");
        }
        asm volatile("s_barrier" ::: "memory");                // tile t visible

        f16x8 ah[4], al[4];
        #pragma unroll
        for (int fm = 0; fm < 4; ++fm) {
            ah[fm] = *reinterpret_cast<const f16x8*>(&sAhi[cur][wr + fm * 16 + lr][kb]);
            al[fm] = *reinterpret_cast<const f16x8*>(&sAlo[cur][wr + fm * 16 + lr][kb]);
        }
        #pragma unroll
        for (int fn = 0; fn < 4; ++fn) {
            const f16x8 bf = *reinterpret_cast<const f16x8*>(&sB[cur][wc + fn * 16 + lr][kb]);
            #pragma unroll
            for (int fm = 0; fm < 4; ++fm) {
                acc[fm][fn] = __builtin_amdgcn_mfma_f32_16x16x32_f16(ah[fm], bf, acc[fm][fn], 0, 0, 0);
                acc[fm][fn] = __builtin_amdgcn_mfma_f32_16x16x32_f16(al[fm], bf, acc[fm][fn], 0, 0, 0);
            }
        }
        asm volatile("s_barrier" ::: "memory");   // WAR fence before restaging [cur]
        cur ^= 1;
    }
#undef STAGE

    const int rg = (l >> 4) * 4;
    #pragma unroll
    for (int fm = 0; fm < 4; ++fm) {
        #pragma unroll
        for (int fn = 0; fn < 4; ++fn) {
            const int row = m0 + wr + fm * 16 + rg;
            const int col = n0 + wc + fn * 16 + lr;
            const float bv = bias ? bias[col] : 0.f;
            #pragma unroll
            for (int rr = 0; rr < 4; ++rr)
                outp[(size_t)(row + rr) * Nt + col] = acc[fm][fn][rr] + bv;
        }
    }
}

// ---------------------------------------------------------------------------
// MFMA spatial attention, f16: QK^T via A=[Khi|Klo], B=[Q|Q] (1 MFMA per 16
// krows, A-side exact); P,V single f16 (error 2^-11, 8x better than bf16).
// 3 MFMAs per (ch,j), simplified softmax (no max-sub), ~41KB LDS.
// ---------------------------------------------------------------------------
__global__ __launch_bounds__(256) void spatial_attn_mfma(
    const float* __restrict__ qkv,
    float* __restrict__ xs_out)
{
    __shared__ unsigned short Kl[224][40];     // f16: Khi(0..15) Klo(16..31) pad
    __shared__ unsigned short Ql[208][24];     // f16: Q(0..15) pad
    __shared__ unsigned short Vt[16][232];     // f16 V^T [d][k]
    __shared__ unsigned short Pb[4][16][40];   // f16 P per wave [q][krow 0..31]

    const int bid = blockIdx.x;                // 1152 = 8*12*12
    const int c = bid % 12;
    const int h = (bid / 12) % 12;
    const int b = bid / 144;
    const int tid = threadIdx.x;
    const int w = tid >> 6, l = tid & 63;
    const int fl = l & 15, g = l >> 4;

    for (int idx = tid; idx < N_ * 16; idx += 256) {
        const int n = idx >> 4, e = idx & 15;
        const float* base = qkv + (size_t)((b * N_ + n) * 12 + c) * NQKV_PAD + 144 + h * 16 + e;
        const float qv = base[0] * 0.25f;
        const float kv = base[192];
        const float vv = base[384];
        const unsigned short kh = f2h(kv);
        Ql[n][e]      = f2h(qv);
        Kl[n][e]      = kh;  Kl[n][16 + e] = f2h(kv - h2f(kh));
        Vt[e][n]      = f2h(vv);
    }
    for (int idx = tid; idx < 16 * 28; idx += 256) {
        const int d = idx / 28, n = 196 + idx % 28;
        Vt[d][n] = 0;
    }
    __syncthreads();

    f32x4 accO[4];
    float lsum[4];
    #pragma unroll
    for (int j = 0; j < 4; ++j) {
        accO[j] = (f32x4){0.f, 0.f, 0.f, 0.f};
        lsum[j] = 0.f;
    }
    const f32x4 zf = (f32x4){0.f, 0.f, 0.f, 0.f};

    for (int ch = 0; ch < 7; ++ch) {
        const int kb0 = ch * 32;
        const f16x8 A1a = *reinterpret_cast<const f16x8*>(&Kl[kb0 + fl][8 * g]);
        const f16x8 A1b = *reinterpret_cast<const f16x8*>(&Kl[kb0 + 16 + fl][8 * g]);
        const f16x8 Av  = *reinterpret_cast<const f16x8*>(&Vt[fl][kb0 + 8 * g]);

        #pragma unroll
        for (int j = 0; j < 4; ++j) {
            const int qt = w + 4 * j;
            if (qt > 12) continue;
            const int qrow = qt * 16 + fl;
            const f16x8 Bq = *reinterpret_cast<const f16x8*>(&Ql[qrow][8 * (g & 1)]);

            f32x4 T0 = __builtin_amdgcn_mfma_f32_16x16x32_f16(A1a, Bq, zf, 0, 0, 0);
            f32x4 T1 = __builtin_amdgcn_mfma_f32_16x16x32_f16(A1b, Bq, zf, 0, 0, 0);

            float s0 = T0[0], s1 = T0[1], s2 = T0[2], s3 = T0[3];
            float s4 = T1[0], s5 = T1[1], s6 = T1[2], s7 = T1[3];
            if (ch == 6) {                      // mask pad k-rows (expf(-1e30)=0)
                const int kg = kb0 + 4 * g;
                if (kg + 0 >= 196) s0 = -1e30f;
                if (kg + 1 >= 196) s1 = -1e30f;
                if (kg + 2 >= 196) s2 = -1e30f;
                if (kg + 3 >= 196) s3 = -1e30f;
                s4 = -1e30f; s5 = -1e30f; s6 = -1e30f; s7 = -1e30f;
            }
            const float p0 = __expf(s0), p1 = __expf(s1);
            const float p2 = __expf(s2), p3 = __expf(s3);
            const float p4 = __expf(s4), p5 = __expf(s5);
            const float p6 = __expf(s6), p7 = __expf(s7);
            lsum[j] += ((p0 + p1) + (p2 + p3)) + ((p4 + p5) + (p6 + p7));

            uint2 wp0, wp1;
            wp0.x = (unsigned)f2h(p0) | ((unsigned)f2h(p1) << 16);
            wp0.y = (unsigned)f2h(p2) | ((unsigned)f2h(p3) << 16);
            wp1.x = (unsigned)f2h(p4) | ((unsigned)f2h(p5) << 16);
            wp1.y = (unsigned)f2h(p6) | ((unsigned)f2h(p7) << 16);
            *reinterpret_cast<uint2*>(&Pb[w][fl][4 * g])      = wp0;   // krows 4g..
            *reinterpret_cast<uint2*>(&Pb[w][fl][16 + 4 * g]) = wp1;   // krows 16+4g..

            const f16x8 Bp = *reinterpret_cast<const f16x8*>(&Pb[w][fl][8 * g]);
            accO[j] = __builtin_amdgcn_mfma_f32_16x16x32_f16(Av, Bp, accO[j], 0, 0, 0);
        }
    }

    #pragma unroll
    for (int j = 0; j < 4; ++j) {
        const int qt = w + 4 * j;
        if (qt > 12) continue;
        float ls = lsum[j];
        ls += __shfl_xor(ls, 16);
        ls += __shfl_xor(ls, 32);
        const int n = qt * 16 + fl;
        if (n < 196) {
            const float inv = 1.f / ls;
            float4 o;
            o.x = accO[j][0] * inv; o.y = accO[j][1] * inv;
            o.z = accO[j][2] * inv; o.w = accO[j][3] * inv;
            const size_t base = ((size_t)((b * 12 + h) * N_ + n) * 12 + c) * 16 + 4 * g;
            *reinterpret_cast<float4*>(&xs_out[base]) = o;
        }
    }
}

// ---------------------------------------------------------------------------
// Channel attention + outer-product combine, 4 rows per 256-thread block.
// Emits y as f16 hi/lo.
// ---------------------------------------------------------------------------
__global__ __launch_bounds__(256) void chan_attn_combine4(
    const float* __restrict__ qkv,
    const float* __restrict__ xs,
    unsigned short* __restrict__ yhi,
    unsigned short* __restrict__ ylo)
{
    const int sub = threadIdx.x >> 6;
    const int t = threadIdx.x & 63;
    const int flat = blockIdx.x * 4 + sub;     // (b*12+h)*196 + n
    const int n = flat % 196;
    const int h = (flat / 196) % 12;
    const int b = flat / 2352;

    __shared__ float sQ[4][12][4], sK[4][12][4], sV[4][12][4], sXc[4][12][4];
    __shared__ float sXs[4][12][16];

    for (int idx = t; idx < 144; idx += 64) {
        const int c = idx / 12, rem = idx % 12, s = rem >> 2, e = rem & 3;
        const float v = qkv[(size_t)((b * N_ + n) * 12 + c) * NQKV_PAD + s * 48 + h * 4 + e];
        if (s == 0) sQ[sub][c][e] = v;
        else if (s == 1) sK[sub][c][e] = v;
        else sV[sub][c][e] = v;
    }
    for (int idx = t; idx < 192; idx += 64) {
        const int c = idx >> 4, j = idx & 15;
        sXs[sub][c][j] = xs[((size_t)flat * 12 + c) * 16 + j];
    }
    __syncthreads();

    if (t < 12) {
        const int c = t;
        float s[12];
        float m = -INFINITY;
        #pragma unroll
        for (int c2 = 0; c2 < 12; ++c2) {
            float d = 0.f;
            #pragma unroll
            for (int e = 0; e < 4; ++e) d += sQ[sub][c][e] * sK[sub][c2][e];
            s[c2] = d * 0.5f;
            m = fmaxf(m, s[c2]);
        }
        float lsum = 0.f;
        #pragma unroll
        for (int c2 = 0; c2 < 12; ++c2) { s[c2] = __expf(s[c2] - m); lsum += s[c2]; }
        const float inv = 1.f / lsum;
        #pragma unroll
        for (int i = 0; i < 4; ++i) {
            float a = 0.f;
            #pragma unroll
            for (int c2 = 0; c2 < 12; ++c2) a += s[c2] * sV[sub][c2][i];
            sXc[sub][c][i] = a * inv;
        }
    }
    __syncthreads();

    const size_t yrow = ((size_t)(b * N_ + n) * 12 + h) * (size_t)D_;
    #pragma unroll
    for (int k = 0; k < 12; ++k) {
        const float v = sXc[sub][k][t >> 4] * sXs[sub][k][t & 15];
        const unsigned short hv = f2h(v);
        yhi[yrow + k * 64 + t] = hv;
        ylo[yrow + k * 64 + t] = f2h(v - h2f(hv));
    }
}

// ---------------------------------------------------------------------------
extern "C" void kernel_launch(void* const* d_in, const int* in_sizes, int n_in,
                              void* d_out, int out_size, void* d_ws, size_t ws_size,
                              hipStream_t stream) {
    const float* x       = (const float*)d_in[0];
    const float* w_qkv_c = (const float*)d_in[1];
    const float* w_qkv_s = (const float*)d_in[2];
    const float* w_proj  = (const float*)d_in[3];
    const float* b_proj  = (const float*)d_in[4];
    float* out = (float*)d_out;

    unsigned short* xhi    = (unsigned short*)d_ws;               // R x 768 f16
    unsigned short* xlo    = xhi + (size_t)R_ * KDIM;
    unsigned short* wqkv_h = xlo + (size_t)R_ * KDIM;             // 768 x 768
    unsigned short* wp_h   = wqkv_h + (size_t)768 * 768;
    float* qkv = (float*)(wp_h + (size_t)768 * 768);              // R x 768 fp32
    float* xs  = qkv + (size_t)R_ * NQKV_PAD;
    unsigned short* yhi = xhi;   // alias: x splits dead after qkv GEMM
    unsigned short* ylo = xlo;

    convert_split<<<(R_ * KDIM) / 1024, 256, 0, stream>>>(x, xhi, xlo, R_ * KDIM);
    convert_weights<<<(2 * 768 * 768) / 1024, 256, 0, stream>>>(
        w_qkv_c, w_qkv_s, w_proj, wqkv_h, wp_h);

    {
        const int mtiles = R_ / BM, ntiles = NQKV_PAD / BN;
        gemm_f16x2<<<mtiles * ntiles, 256, 0, stream>>>(
            xhi, xlo, wqkv_h, nullptr, qkv, R_, NQKV_PAD, KDIM, ntiles);
    }
    spatial_attn_mfma<<<B_ * H_ * C_, 256, 0, stream>>>(qkv, xs);
    chan_attn_combine4<<<(B_ * H_ * N_) / 4, 256, 0, stream>>>(qkv, xs, yhi, ylo);
    {
        const int mtiles = R_ / BM, ntiles = D_ / BN;
        gemm_f16x2<<<mtiles * ntiles, 256, 0, stream>>>(
            yhi, ylo, wp_h, b_proj, out, R_, D_, KDIM, ntiles);
    }
}

// Round 14
// 170.686 us; speedup vs baseline: 1.9339x; 1.2570x over previous
//
#include <hip/hip_runtime.h>
#include <math.h>

// Problem constants
#define B_  8
#define N_  196
#define C_  12
#define D_  768
#define H_  12
#define R_  (B_*N_*C_)      // 18816 rows
#define KDIM 768
#define NQKV_PAD 768        // 720 real qkv cols padded to 768

typedef _Float16 f16x8 __attribute__((ext_vector_type(8)));   // 8 f16 = 4 VGPR
typedef __attribute__((ext_vector_type(4))) float f32x4;

__device__ inline unsigned short f2h(float f) {
    union { _Float16 h; unsigned short u; } v; v.h = (_Float16)f; return v.u;
}
__device__ inline float h2f(unsigned short u) {
    union { unsigned short u; _Float16 h; } v; v.u = u; return (float)v.h;
}

// ---------------------------------------------------------------------------
// fp32 -> f16 elementwise. n must be a multiple of 4.
// ---------------------------------------------------------------------------
__global__ __launch_bounds__(256) void convert_f16(
    const float* __restrict__ in, unsigned short* __restrict__ outh, int n)
{
    int i = (blockIdx.x * 256 + threadIdx.x) * 4;
    if (i >= n) return;
    float4 v = *reinterpret_cast<const float4*>(in + i);
    ushort4 h;
    h.x = f2h(v.x); h.y = f2h(v.y); h.z = f2h(v.z); h.w = f2h(v.w);
    *reinterpret_cast<ushort4*>(outh + i) = h;
}

// One launch: wqkv (packed 768x768, rows 720+ zero) and wp, single f16 each.
__global__ __launch_bounds__(256) void convert_weights(
    const float* __restrict__ wc, const float* __restrict__ ws,
    const float* __restrict__ wp,
    unsigned short* __restrict__ wqkv_h, unsigned short* __restrict__ wp_h)
{
    int i = (blockIdx.x * 256 + threadIdx.x) * 4;
    unsigned short* dh; float4 v; int off;
    if (i < 768 * 768) {
        const int r = i / 768, k = i % 768;
        v = make_float4(0.f, 0.f, 0.f, 0.f);
        if (r < 144)      v = *reinterpret_cast<const float4*>(wc + r * 768 + k);
        else if (r < 720) v = *reinterpret_cast<const float4*>(ws + (r - 144) * 768 + k);
        dh = wqkv_h; off = i;
    } else {
        off = i - 768 * 768;
        if (off >= 768 * 768) return;
        v = *reinterpret_cast<const float4*>(wp + off);
        dh = wp_h;
    }
    ushort4 h;
    h.x = f2h(v.x); h.y = f2h(v.y); h.z = f2h(v.z); h.w = f2h(v.w);
    *reinterpret_cast<ushort4*>(dh + off) = h;
}

// ---------------------------------------------------------------------------
// Plain single-f16 MFMA GEMM: out = Ah @ Bh^T. r13-verified structure:
// 2-phase dbuf, counted vmcnt, chunked XCD swizzle, nt-fast.
// LDS 32KB -> up to 5 blocks/CU; 4 staged loads/step; 16 MFMA/step/wave.
// ---------------------------------------------------------------------------
#define BM 128
#define BN 128
#define BK 32

__device__ inline void gload16(const unsigned short* src, void* ldsbase) {
    __builtin_amdgcn_global_load_lds(
        (const __attribute__((address_space(1))) unsigned int*)src,
        (__attribute__((address_space(3))) unsigned int*)ldsbase, 16, 0, 0);
}

__global__ __launch_bounds__(256) void gemm_f16(
    const unsigned short* __restrict__ Ah, const unsigned short* __restrict__ Bh,
    const float* __restrict__ bias,
    float* __restrict__ outp, int M, int Nt, int K, int ntiles)
{
    __shared__ unsigned short sA[2][BM][BK], sB[2][BN][BK];

    const int nwg = gridDim.x;
    const int bid = blockIdx.x;
    const int xcd = bid & 7, slot = bid >> 3;
    const int q = nwg >> 3, r = nwg & 7;
    const int wg = (xcd < r ? xcd * (q + 1) : r * (q + 1) + (xcd - r) * q) + slot;
    const int mt = wg / ntiles, nt = wg - mt * ntiles;   // nt fast: A-panel reuse
    const int m0 = mt * BM, n0 = nt * BN;

    const int tid = threadIdx.x;
    const int w = tid >> 6, l = tid & 63;
    const int wr = (w >> 1) * 64, wc = (w & 1) * 64;

    f32x4 acc[4][4];
    #pragma unroll
    for (int i = 0; i < 4; ++i)
        #pragma unroll
        for (int j = 0; j < 4; ++j)
            acc[i][j] = (f32x4){0.f, 0.f, 0.f, 0.f};

    const int seg0 = w * 1024, seg1 = 4096 + w * 1024;
    const int o0 = seg0 + l * 16, o1 = seg1 + l * 16;
    const int r0 = o0 >> 6, c0 = (o0 & 63) >> 1;
    const int r1 = o1 >> 6, c1 = (o1 & 63) >> 1;

    const int lr = l & 15;
    const int kb = (l >> 4) * 8;

#define STAGE(buf, kk)                                                                   \
    gload16(Ah + (size_t)(m0 + r0) * K + (kk) + c0, (char*)sA + (buf) * 8192 + seg0);    \
    gload16(Ah + (size_t)(m0 + r1) * K + (kk) + c1, (char*)sA + (buf) * 8192 + seg1);    \
    gload16(Bh + (size_t)(n0 + r0) * K + (kk) + c0, (char*)sB + (buf) * 8192 + seg0);    \
    gload16(Bh + (size_t)(n0 + r1) * K + (kk) + c1, (char*)sB + (buf) * 8192 + seg1);

    STAGE(0, 0);                       // 4 loads in flight

    const int KT = K / BK;             // 24
    int cur = 0;
    for (int t = 0; t < KT; ++t) {
        if (t + 1 < KT) {
            STAGE(cur ^ 1, (t + 1) * BK);                      // +4 -> 8 in flight
            asm volatile("s_waitcnt vmcnt(4)" ::: "memory");   // drain tile t only
        } else {
            asm volatile("s_waitcnt vmcnt(0)" ::: "memory");
        }
        asm volatile("s_barrier" ::: "memory");                // tile t visible

        f16x8 ah[4];
        #pragma unroll
        for (int fm = 0; fm < 4; ++fm)
            ah[fm] = *reinterpret_cast<const f16x8*>(&sA[cur][wr + fm * 16 + lr][kb]);
        #pragma unroll
        for (int fn = 0; fn < 4; ++fn) {
            const f16x8 bf = *reinterpret_cast<const f16x8*>(&sB[cur][wc + fn * 16 + lr][kb]);
            #pragma unroll
            for (int fm = 0; fm < 4; ++fm)
                acc[fm][fn] = __builtin_amdgcn_mfma_f32_16x16x32_f16(ah[fm], bf, acc[fm][fn], 0, 0, 0);
        }
        asm volatile("s_barrier" ::: "memory");   // WAR fence before restaging [cur]
        cur ^= 1;
    }
#undef STAGE

    const int rg = (l >> 4) * 4;
    #pragma unroll
    for (int fm = 0; fm < 4; ++fm) {
        #pragma unroll
        for (int fn = 0; fn < 4; ++fn) {
            const int row = m0 + wr + fm * 16 + rg;
            const int col = n0 + wc + fn * 16 + lr;
            const float bv = bias ? bias[col] : 0.f;
            #pragma unroll
            for (int rr = 0; rr < 4; ++rr)
                outp[(size_t)(row + rr) * Nt + col] = acc[fm][fn][rr] + bv;
        }
    }
}

// ---------------------------------------------------------------------------
// MFMA spatial attention (r13-verified, unchanged): QK^T via A=[Khi|Klo],
// B=[Q|Q]; P,V single f16; simplified softmax (no max-sub).
// ---------------------------------------------------------------------------
__global__ __launch_bounds__(256) void spatial_attn_mfma(
    const float* __restrict__ qkv,
    float* __restrict__ xs_out)
{
    __shared__ unsigned short Kl[224][40];     // f16: Khi(0..15) Klo(16..31) pad
    __shared__ unsigned short Ql[208][24];     // f16: Q(0..15) pad
    __shared__ unsigned short Vt[16][232];     // f16 V^T [d][k]
    __shared__ unsigned short Pb[4][16][40];   // f16 P per wave [q][krow 0..31]

    const int bid = blockIdx.x;                // 1152 = 8*12*12
    const int c = bid % 12;
    const int h = (bid / 12) % 12;
    const int b = bid / 144;
    const int tid = threadIdx.x;
    const int w = tid >> 6, l = tid & 63;
    const int fl = l & 15, g = l >> 4;

    for (int idx = tid; idx < N_ * 16; idx += 256) {
        const int n = idx >> 4, e = idx & 15;
        const float* base = qkv + (size_t)((b * N_ + n) * 12 + c) * NQKV_PAD + 144 + h * 16 + e;
        const float qv = base[0] * 0.25f;
        const float kv = base[192];
        const float vv = base[384];
        const unsigned short kh = f2h(kv);
        Ql[n][e]      = f2h(qv);
        Kl[n][e]      = kh;  Kl[n][16 + e] = f2h(kv - h2f(kh));
        Vt[e][n]      = f2h(vv);
    }
    for (int idx = tid; idx < 16 * 28; idx += 256) {
        const int d = idx / 28, n = 196 + idx % 28;
        Vt[d][n] = 0;
    }
    __syncthreads();

    f32x4 accO[4];
    float lsum[4];
    #pragma unroll
    for (int j = 0; j < 4; ++j) {
        accO[j] = (f32x4){0.f, 0.f, 0.f, 0.f};
        lsum[j] = 0.f;
    }
    const f32x4 zf = (f32x4){0.f, 0.f, 0.f, 0.f};

    for (int ch = 0; ch < 7; ++ch) {
        const int kb0 = ch * 32;
        const f16x8 A1a = *reinterpret_cast<const f16x8*>(&Kl[kb0 + fl][8 * g]);
        const f16x8 A1b = *reinterpret_cast<const f16x8*>(&Kl[kb0 + 16 + fl][8 * g]);
        const f16x8 Av  = *reinterpret_cast<const f16x8*>(&Vt[fl][kb0 + 8 * g]);

        #pragma unroll
        for (int j = 0; j < 4; ++j) {
            const int qt = w + 4 * j;
            if (qt > 12) continue;
            const int qrow = qt * 16 + fl;
            const f16x8 Bq = *reinterpret_cast<const f16x8*>(&Ql[qrow][8 * (g & 1)]);

            f32x4 T0 = __builtin_amdgcn_mfma_f32_16x16x32_f16(A1a, Bq, zf, 0, 0, 0);
            f32x4 T1 = __builtin_amdgcn_mfma_f32_16x16x32_f16(A1b, Bq, zf, 0, 0, 0);

            float s0 = T0[0], s1 = T0[1], s2 = T0[2], s3 = T0[3];
            float s4 = T1[0], s5 = T1[1], s6 = T1[2], s7 = T1[3];
            if (ch == 6) {                      // mask pad k-rows (expf(-1e30)=0)
                const int kg = kb0 + 4 * g;
                if (kg + 0 >= 196) s0 = -1e30f;
                if (kg + 1 >= 196) s1 = -1e30f;
                if (kg + 2 >= 196) s2 = -1e30f;
                if (kg + 3 >= 196) s3 = -1e30f;
                s4 = -1e30f; s5 = -1e30f; s6 = -1e30f; s7 = -1e30f;
            }
            const float p0 = __expf(s0), p1 = __expf(s1);
            const float p2 = __expf(s2), p3 = __expf(s3);
            const float p4 = __expf(s4), p5 = __expf(s5);
            const float p6 = __expf(s6), p7 = __expf(s7);
            lsum[j] += ((p0 + p1) + (p2 + p3)) + ((p4 + p5) + (p6 + p7));

            uint2 wp0, wp1;
            wp0.x = (unsigned)f2h(p0) | ((unsigned)f2h(p1) << 16);
            wp0.y = (unsigned)f2h(p2) | ((unsigned)f2h(p3) << 16);
            wp1.x = (unsigned)f2h(p4) | ((unsigned)f2h(p5) << 16);
            wp1.y = (unsigned)f2h(p6) | ((unsigned)f2h(p7) << 16);
            *reinterpret_cast<uint2*>(&Pb[w][fl][4 * g])      = wp0;   // krows 4g..
            *reinterpret_cast<uint2*>(&Pb[w][fl][16 + 4 * g]) = wp1;   // krows 16+4g..

            const f16x8 Bp = *reinterpret_cast<const f16x8*>(&Pb[w][fl][8 * g]);
            accO[j] = __builtin_amdgcn_mfma_f32_16x16x32_f16(Av, Bp, accO[j], 0, 0, 0);
        }
    }

    #pragma unroll
    for (int j = 0; j < 4; ++j) {
        const int qt = w + 4 * j;
        if (qt > 12) continue;
        float ls = lsum[j];
        ls += __shfl_xor(ls, 16);
        ls += __shfl_xor(ls, 32);
        const int n = qt * 16 + fl;
        if (n < 196) {
            const float inv = 1.f / ls;
            float4 o;
            o.x = accO[j][0] * inv; o.y = accO[j][1] * inv;
            o.z = accO[j][2] * inv; o.w = accO[j][3] * inv;
            const size_t base = ((size_t)((b * 12 + h) * N_ + n) * 12 + c) * 16 + 4 * g;
            *reinterpret_cast<float4*>(&xs_out[base]) = o;
        }
    }
}

// ---------------------------------------------------------------------------
// Channel attention + outer-product combine, 4 rows per 256-thread block.
// Emits y as single f16.
// ---------------------------------------------------------------------------
__global__ __launch_bounds__(256) void chan_attn_combine4(
    const float* __restrict__ qkv,
    const float* __restrict__ xs,
    unsigned short* __restrict__ yh)
{
    const int sub = threadIdx.x >> 6;
    const int t = threadIdx.x & 63;
    const int flat = blockIdx.x * 4 + sub;     // (b*12+h)*196 + n
    const int n = flat % 196;
    const int h = (flat / 196) % 12;
    const int b = flat / 2352;

    __shared__ float sQ[4][12][4], sK[4][12][4], sV[4][12][4], sXc[4][12][4];
    __shared__ float sXs[4][12][16];

    for (int idx = t; idx < 144; idx += 64) {
        const int c = idx / 12, rem = idx % 12, s = rem >> 2, e = rem & 3;
        const float v = qkv[(size_t)((b * N_ + n) * 12 + c) * NQKV_PAD + s * 48 + h * 4 + e];
        if (s == 0) sQ[sub][c][e] = v;
        else if (s == 1) sK[sub][c][e] = v;
        else sV[sub][c][e] = v;
    }
    for (int idx = t; idx < 192; idx += 64) {
        const int c = idx >> 4, j = idx & 15;
        sXs[sub][c][j] = xs[((size_t)flat * 12 + c) * 16 + j];
    }
    __syncthreads();

    if (t < 12) {
        const int c = t;
        float s[12];
        float m = -INFINITY;
        #pragma unroll
        for (int c2 = 0; c2 < 12; ++c2) {
            float d = 0.f;
            #pragma unroll
            for (int e = 0; e < 4; ++e) d += sQ[sub][c][e] * sK[sub][c2][e];
            s[c2] = d * 0.5f;
            m = fmaxf(m, s[c2]);
        }
        float lsum = 0.f;
        #pragma unroll
        for (int c2 = 0; c2 < 12; ++c2) { s[c2] = __expf(s[c2] - m); lsum += s[c2]; }
        const float inv = 1.f / lsum;
        #pragma unroll
        for (int i = 0; i < 4; ++i) {
            float a = 0.f;
            #pragma unroll
            for (int c2 = 0; c2 < 12; ++c2) a += s[c2] * sV[sub][c2][i];
            sXc[sub][c][i] = a * inv;
        }
    }
    __syncthreads();

    const size_t yrow = ((size_t)(b * N_ + n) * 12 + h) * (size_t)D_;
    #pragma unroll
    for (int k = 0; k < 12; ++k) {
        const float v = sXc[sub][k][t >> 4] * sXs[sub][k][t & 15];
        yh[yrow + k * 64 + t] = f2h(v);
    }
}

// ---------------------------------------------------------------------------
extern "C" void kernel_launch(void* const* d_in, const int* in_sizes, int n_in,
                              void* d_out, int out_size, void* d_ws, size_t ws_size,
                              hipStream_t stream) {
    const float* x       = (const float*)d_in[0];
    const float* w_qkv_c = (const float*)d_in[1];
    const float* w_qkv_s = (const float*)d_in[2];
    const float* w_proj  = (const float*)d_in[3];
    const float* b_proj  = (const float*)d_in[4];
    float* out = (float*)d_out;

    unsigned short* xh     = (unsigned short*)d_ws;               // R x 768 f16
    unsigned short* wqkv_h = xh + (size_t)R_ * KDIM;              // 768 x 768
    unsigned short* wp_h   = wqkv_h + (size_t)768 * 768;
    float* qkv = (float*)(wp_h + (size_t)768 * 768);              // R x 768 fp32
    float* xs  = qkv + (size_t)R_ * NQKV_PAD;
    unsigned short* yh = xh;   // alias: x f16 dead after qkv GEMM

    convert_f16<<<(R_ * KDIM) / 1024, 256, 0, stream>>>(x, xh, R_ * KDIM);
    convert_weights<<<(2 * 768 * 768) / 1024, 256, 0, stream>>>(
        w_qkv_c, w_qkv_s, w_proj, wqkv_h, wp_h);

    {
        const int mtiles = R_ / BM, ntiles = NQKV_PAD / BN;
        gemm_f16<<<mtiles * ntiles, 256, 0, stream>>>(
            xh, wqkv_h, nullptr, qkv, R_, NQKV_PAD, KDIM, ntiles);
    }
    spatial_attn_mfma<<<B_ * H_ * C_, 256, 0, stream>>>(qkv, xs);
    chan_attn_combine4<<<(B_ * H_ * N_) / 4, 256, 0, stream>>>(qkv, xs, yh);
    {
        const int mtiles = R_ / BM, ntiles = D_ / BN;
        gemm_f16<<<mtiles * ntiles, 256, 0, stream>>>(
            yh, wp_h, b_proj, out, R_, D_, KDIM, ntiles);
    }
}